// Round 7
// baseline (820.854 us; speedup 1.0000x reference)
//
#include <hip/hip_runtime.h>

// GraphSAGEConv for MI355X (gfx950) — R7: two-kernel split.
//
// Math (exact up to fp32 reassociation):
//   out = relu( nf @ Wl1 + (mean_s nf[src]) @ Wl2 + (mean_s ef) @ (W_edge @ Wl2)
//               + (b_edge @ Wl2 + b_lin) )
// K1 (sage_aggregate): agg[n][0:128] = mean_s nf[src[n,s]]; agg[n][128:192] = mean_s ef[n,s].
//   Pure streaming: no LDS, no barriers, grid-stride, all accesses coalesced.
// K2 (sage_gemm): out = relu([nf | agg] @ [Wl1; Wl2; Wcomb] + b_comb), K=320,
//   staged 2 chunks (128 nf / 192 agg) through LDS buf[64][196]; lane=node,
//   wave owns 16 cols, W streamed wave-uniform (s_load).
// R6 lesson: launch_bounds(512,8) forced acc spill (WRITE +32MB, VGPR 32).
//   Here K2 uses (512,6) — cap ~85 VGPR >> demand ~48 — occupancy set by LDS
//   (3 blocks/CU), not by register starvation.

#define NODES    100000
#define NSAMP    16
#define NODE_DIM 128
#define EDGE_DIM 64
#define EMB_DIM  128
#define AGGC     192            // agg row: 128 nfagg + 64 efagg
#define BN       64
#define THREADS  512
#define BSTRIDE  196            // 192 + 4 pad; 196%32==4 -> b128 reads tile 128B windows conflict-free

// ---------------------------------------------------------------------------
// prep: Wcat[320][128] = [Wl1(128); Wl2(128); Wcomb=W_edge@Wl2 (64)]; b_comb.
// ---------------------------------------------------------------------------
__global__ __launch_bounds__(128) void prep_weights(
    const float* __restrict__ W_edge, const float* __restrict__ b_edge,
    const float* __restrict__ W_lin,  const float* __restrict__ b_lin,
    float* __restrict__ Wcat, float* __restrict__ b_comb)
{
    const int r = blockIdx.x;
    const int j = threadIdx.x;
    if (r < 256) {
        Wcat[r * 128 + j] = W_lin[r * 128 + j];
    } else if (r < 320) {
        const int e = r - 256;
        float s = 0.f;
        #pragma unroll 4
        for (int k = 0; k < 128; ++k)
            s = fmaf(W_edge[e * 128 + k], W_lin[(128 + k) * 128 + j], s);
        Wcat[r * 128 + j] = s;
    } else {
        float s = b_lin[j];
        #pragma unroll 4
        for (int k = 0; k < 128; ++k)
            s = fmaf(b_edge[k], W_lin[(128 + k) * 128 + j], s);
        b_comb[j] = s;
    }
}

// ---------------------------------------------------------------------------
// K1: aggregation. Loop E (edge-mean) streams the 410 MB edge tensor once;
// loop G (gather-mean) reads nf rows via L3 (nf = 51 MB, L3-resident).
// Mappings put the minor index across lanes so reads AND writes coalesce.
// ---------------------------------------------------------------------------
__global__ __launch_bounds__(256, 6) void sage_aggregate(
    const float* __restrict__ node_feat,
    const float* __restrict__ edge_feat,
    const int*   __restrict__ src_idx,
    float* __restrict__ agg)
{
    const int g      = blockIdx.x * blockDim.x + threadIdx.x;
    const int stride = gridDim.x * blockDim.x;

    // ---- loop E: item = n*16 + q, q minor. Lanes 0-15 read 256B contiguous
    //      per sample row; wave covers 4 nodes. Each edge byte read once.
    for (int item = g; item < NODES * 16; item += stride) {
        const int n = item >> 4;
        const int q = item & 15;
        const float* ep = edge_feat + (size_t)n * (NSAMP * EDGE_DIM) + q * 4;
        float4 a0 = {0,0,0,0}, a1 = {0,0,0,0};
        #pragma unroll
        for (int s = 0; s < NSAMP; s += 2) {
            const float4 v0 = *reinterpret_cast<const float4*>(ep + s * EDGE_DIM);
            const float4 v1 = *reinterpret_cast<const float4*>(ep + (s + 1) * EDGE_DIM);
            a0.x += v0.x; a0.y += v0.y; a0.z += v0.z; a0.w += v0.w;
            a1.x += v1.x; a1.y += v1.y; a1.z += v1.z; a1.w += v1.w;
        }
        float4 a;
        a.x = (a0.x + a1.x) * 0.0625f; a.y = (a0.y + a1.y) * 0.0625f;
        a.z = (a0.z + a1.z) * 0.0625f; a.w = (a0.w + a1.w) * 0.0625f;
        *reinterpret_cast<float4*>(agg + (size_t)n * AGGC + 128 + q * 4) = a;
    }

    // ---- loop G: item = n*32 + q, q minor. Per sample, lanes 0-31 read one
    //      full 512B nf row contiguously; idx loads broadcast within the group.
    for (int item = g; item < NODES * 32; item += stride) {
        const int n = item >> 5;
        const int q = item & 31;
        const int4* ip = reinterpret_cast<const int4*>(src_idx + n * NSAMP);
        const int4 i0 = ip[0], i1 = ip[1], i2 = ip[2], i3 = ip[3];
        const float* nfq = node_feat + q * 4;
        float4 a0 = {0,0,0,0}, a1 = {0,0,0,0};
#define GACC(A_, R_) {                                                         \
        const float4 v = *reinterpret_cast<const float4*>(                     \
            nfq + (size_t)(R_) * NODE_DIM);                                    \
        A_.x += v.x; A_.y += v.y; A_.z += v.z; A_.w += v.w; }
        GACC(a0, i0.x) GACC(a1, i0.y) GACC(a0, i0.z) GACC(a1, i0.w)
        GACC(a0, i1.x) GACC(a1, i1.y) GACC(a0, i1.z) GACC(a1, i1.w)
        GACC(a0, i2.x) GACC(a1, i2.y) GACC(a0, i2.z) GACC(a1, i2.w)
        GACC(a0, i3.x) GACC(a1, i3.y) GACC(a0, i3.z) GACC(a1, i3.w)
#undef GACC
        float4 a;
        a.x = (a0.x + a1.x) * 0.0625f; a.y = (a0.y + a1.y) * 0.0625f;
        a.z = (a0.z + a1.z) * 0.0625f; a.w = (a0.w + a1.w) * 0.0625f;
        *reinterpret_cast<float4*>(agg + (size_t)n * AGGC + q * 4) = a;
    }
}

// ---------------------------------------------------------------------------
// K2: [N,320] @ [320,128] GEMM. Block = 64 nodes x 128 cols, 8 waves.
// lane = node; wave w owns cols [16w,16w+16); W rows wave-uniform -> s_load.
// ---------------------------------------------------------------------------
__global__ __launch_bounds__(THREADS, 6) void sage_gemm(
    const float* __restrict__ node_feat,
    const float* __restrict__ agg,
    const float* __restrict__ Wcat,
    const float* __restrict__ b_comb,
    float* __restrict__ out)
{
    __shared__ float buf[BN][BSTRIDE];     // 49.0 KB -> 3 blocks/CU

    const int t      = threadIdx.x;
    const int base   = blockIdx.x * BN;
    const int nvalid = min(BN, NODES - base);

    // ---- chunk0 stage: nf rows -> buf[:, 0:128] (2048 float4, coalesced) ----
    #pragma unroll
    for (int p = 0; p < 4; ++p) {
        const int item = t + p * THREADS;  // 0..2047
        const int n  = item >> 5;
        const int kq = item & 31;
        float4 v = {0,0,0,0};
        if (n < nvalid)
            v = *reinterpret_cast<const float4*>(
                    node_feat + (size_t)(base + n) * NODE_DIM + kq * 4);
        *reinterpret_cast<float4*>(&buf[n][kq * 4]) = v;
    }

    __syncthreads();

    const int lane = t & 63;
    const int w    = t >> 6;
    const int wcol = __builtin_amdgcn_readfirstlane(w * 16);
    const float* __restrict__ bp = b_comb + wcol;

    float acc[16];
    #pragma unroll
    for (int j = 0; j < 16; ++j) acc[j] = 0.f;

#define GEMM_PASS(W_, rowBase_)                                                \
    {                                                                          \
        const float* __restrict__ Wp = Wcat + (rowBase_) * EMB_DIM + wcol;     \
        for (int k = 0; k < (W_); k += 4) {                                    \
            const float4 in4 = *reinterpret_cast<const float4*>(&buf[lane][k]);\
            const float in_[4] = { in4.x, in4.y, in4.z, in4.w };               \
            _Pragma("unroll")                                                  \
            for (int kk = 0; kk < 4; ++kk) {                                   \
                const float* wr = Wp + (k + kk) * EMB_DIM;                     \
                _Pragma("unroll")                                              \
                for (int j = 0; j < 16; ++j)                                   \
                    acc[j] = fmaf(in_[kk], wr[j], acc[j]);                     \
            }                                                                  \
        }                                                                      \
    }

    // ---- GEMM pass 0: k 0..127 (self, Wl1 rows) ----
    GEMM_PASS(128, 0)
    __syncthreads();

    // ---- chunk1 stage: agg rows (192 cols) -> buf[:, 0:192] (3072 float4) ----
    #pragma unroll
    for (int p = 0; p < 6; ++p) {
        const int item = t + p * THREADS;  // 0..3071
        const int n  = item / 48;
        const int kq = item - n * 48;
        float4 v = {0,0,0,0};
        if (n < nvalid)
            v = *reinterpret_cast<const float4*>(
                    agg + (size_t)(base + n) * AGGC + kq * 4);
        *reinterpret_cast<float4*>(&buf[n][kq * 4]) = v;
    }

    __syncthreads();

    // ---- GEMM pass 1: k 128..319 (agg, [Wl2; Wcomb] rows) ----
    GEMM_PASS(192, 128)

    // ---- epilogue ----
    if (lane < nvalid) {
        float* op = out + (size_t)(base + lane) * EMB_DIM + wcol;
        #pragma unroll
        for (int jq = 0; jq < 4; ++jq) {
            float4 v;
            v.x = fmaxf(acc[jq * 4 + 0] + bp[jq * 4 + 0], 0.f);
            v.y = fmaxf(acc[jq * 4 + 1] + bp[jq * 4 + 1], 0.f);
            v.z = fmaxf(acc[jq * 4 + 2] + bp[jq * 4 + 2], 0.f);
            v.w = fmaxf(acc[jq * 4 + 3] + bp[jq * 4 + 3], 0.f);
            *reinterpret_cast<float4*>(op + jq * 4) = v;
        }
    }
#undef GEMM_PASS
}

// ---------------------------------------------------------------------------
extern "C" void kernel_launch(void* const* d_in, const int* in_sizes, int n_in,
                              void* d_out, int out_size, void* d_ws, size_t ws_size,
                              hipStream_t stream)
{
    const float* node_feat = (const float*)d_in[0];  // [N,128]
    const float* edge_feat = (const float*)d_in[1];  // [E,64]
    const int*   src_idx   = (const int*)  d_in[2];  // [E]
    const float* W_edge    = (const float*)d_in[3];  // [64,128]
    const float* b_edge    = (const float*)d_in[4];  // [128]
    const float* W_lin     = (const float*)d_in[5];  // [256,128]
    const float* b_lin     = (const float*)d_in[6];  // [128]
    float* out = (float*)d_out;                      // [N,128]

    float* agg    = (float*)d_ws;                    // N*192 floats = 76.8 MB
    float* Wcat   = agg + (size_t)NODES * AGGC;      // 320*128 floats
    float* b_comb = Wcat + 320 * EMB_DIM;            // 128 floats

    // K1: longest stream first; prep (tiny) fills the gap before K2 needs W.
    sage_aggregate<<<dim3(2048), dim3(256), 0, stream>>>(
        node_feat, edge_feat, src_idx, agg);

    prep_weights<<<dim3(321), dim3(128), 0, stream>>>(
        W_edge, b_edge, W_lin, b_lin, Wcat, b_comb);

    const int nblocks = (NODES + BN - 1) / BN;       // 1563
    sage_gemm<<<dim3(nblocks), dim3(THREADS), 0, stream>>>(
        node_feat, agg, Wcat, b_comb, out);
}